// Round 5
// baseline (26.396 us; speedup 1.0000x reference)
//
#include <hip/hip_runtime.h>
#include <hip/hip_fp16.h>

// TensorCPFactorization: value[b] = sum_r prod_i f_i[idx[b,i], r]
// DIM=512, RANK=256, ORDER=4, BATCH=100000, f32 factors.
//
// R5: f16 factors (convert pass into d_ws) + R2's proven gather shape:
// one wave64 per 4 elements, each factor-row load = 64 lanes x 8B (uint2,
// 4 f16/lane) = ONE contiguous 512B segment. R4's half-wave 2-segment
// loads ran at 19 B/clk/CU; R2's single-segment shape ran at the 32 B/clk
// per-CU L2-return port. Same instruction count as R2, half the bytes.

#define RANK   256
#define FELEMS (512 * 256)   // elements per factor
#define EPW    4             // elements per wave

// ---- pass 1: f32 -> f16 conversion into d_ws ------------------------------
__global__ __launch_bounds__(256) void cp_convert_f16(
    const float* __restrict__ f0, const float* __restrict__ f1,
    const float* __restrict__ f2, const float* __restrict__ f3,
    __half* __restrict__ ws)
{
    const float* srcs[4] = {f0, f1, f2, f3};
    const float* __restrict__ src = srcs[blockIdx.y];
    __half* __restrict__ dst = ws + (size_t)blockIdx.y * FELEMS;

    const int base = (blockIdx.x * 256 + threadIdx.x) * 8;
    if (base >= FELEMS) return;

    const float4 a = *reinterpret_cast<const float4*>(src + base);
    const float4 b = *reinterpret_cast<const float4*>(src + base + 4);
    union { uint4 u; __half2 h[4]; } pk;
    pk.h[0] = __float22half2_rn(make_float2(a.x, a.y));
    pk.h[1] = __float22half2_rn(make_float2(a.z, a.w));
    pk.h[2] = __float22half2_rn(make_float2(b.x, b.y));
    pk.h[3] = __float22half2_rn(make_float2(b.z, b.w));
    *reinterpret_cast<uint4*>(dst + base) = pk.u;
}

// ---- pass 2: gather + dot over f16 rows (R2 shape) ------------------------
__device__ __forceinline__ void cvt4(const uint2 u, float* v) {
    const __half2* h = reinterpret_cast<const __half2*>(&u);
    float2 t;
    t = __half22float2(h[0]); v[0] = t.x; v[1] = t.y;
    t = __half22float2(h[1]); v[2] = t.x; v[3] = t.y;
}

__global__ __launch_bounds__(256) void cp_gather_f16(
    const __half* __restrict__ ws, const int* __restrict__ idx,
    float* __restrict__ out, int batch)
{
    const int wid  = (int)((blockIdx.x * blockDim.x + threadIdx.x) >> 6);
    const int lane = (int)(threadIdx.x & 63);
    const int e0   = wid * EPW;
    if (e0 >= batch) return;   // batch % 4 == 0

    const int r = lane * 4;    // 4 rank entries per lane, 64 lanes = full row

    // Index vectors for the 4 elements (wave-uniform broadcast loads).
    int4 iv[EPW];
    #pragma unroll
    for (int e = 0; e < EPW; ++e)
        iv[e] = *reinterpret_cast<const int4*>(idx + (size_t)(e0 + e) * 4);

    // 16 row loads, each one contiguous 512B segment (64 lanes x 8B).
    uint2 raw[EPW][4];
    #pragma unroll
    for (int e = 0; e < EPW; ++e) {
        raw[e][0] = *reinterpret_cast<const uint2*>(ws + 0 * FELEMS + (size_t)iv[e].x * RANK + r);
        raw[e][1] = *reinterpret_cast<const uint2*>(ws + 1 * FELEMS + (size_t)iv[e].y * RANK + r);
        raw[e][2] = *reinterpret_cast<const uint2*>(ws + 2 * FELEMS + (size_t)iv[e].z * RANK + r);
        raw[e][3] = *reinterpret_cast<const uint2*>(ws + 3 * FELEMS + (size_t)iv[e].w * RANK + r);
    }

    float s[EPW];
    #pragma unroll
    for (int e = 0; e < EPW; ++e) {
        float va[4], vb[4], vc[4], vd[4];
        cvt4(raw[e][0], va);
        cvt4(raw[e][1], vb);
        cvt4(raw[e][2], vc);
        cvt4(raw[e][3], vd);
        float acc = 0.f;
        #pragma unroll
        for (int k = 0; k < 4; ++k)
            acc += va[k] * vb[k] * vc[k] * vd[k];
        s[e] = acc;
    }

    // 4 independent 64-lane butterfly reductions.
    #pragma unroll
    for (int off = 32; off > 0; off >>= 1) {
        #pragma unroll
        for (int e = 0; e < EPW; ++e)
            s[e] += __shfl_xor(s[e], off);
    }

    if (lane == 0)
        *reinterpret_cast<float4*>(out + e0) = make_float4(s[0], s[1], s[2], s[3]);
}

// ---- fallback: R2 f32 kernel (used only if ws is too small) ---------------
__global__ __launch_bounds__(256) void cp_gather_f32(
    const float* __restrict__ f0, const float* __restrict__ f1,
    const float* __restrict__ f2, const float* __restrict__ f3,
    const int*   __restrict__ idx,
    float*       __restrict__ out, int batch)
{
    const int wid  = (int)((blockIdx.x * blockDim.x + threadIdx.x) >> 6);
    const int lane = (int)(threadIdx.x & 63);
    const int e0   = wid * 4;
    if (e0 >= batch) return;
    const int r = lane * 4;
    float s[4];
    #pragma unroll
    for (int e = 0; e < 4; ++e) {
        const int  ec = (e0 + e) < batch ? (e0 + e) : batch - 1;
        const int4 iv = *reinterpret_cast<const int4*>(idx + (size_t)ec * 4);
        const float4 a = *reinterpret_cast<const float4*>(f0 + (size_t)iv.x * RANK + r);
        const float4 b = *reinterpret_cast<const float4*>(f1 + (size_t)iv.y * RANK + r);
        const float4 c = *reinterpret_cast<const float4*>(f2 + (size_t)iv.z * RANK + r);
        const float4 d = *reinterpret_cast<const float4*>(f3 + (size_t)iv.w * RANK + r);
        s[e] = a.x * b.x * c.x * d.x + a.y * b.y * c.y * d.y
             + a.z * b.z * c.z * d.z + a.w * b.w * c.w * d.w;
    }
    #pragma unroll
    for (int off = 32; off > 0; off >>= 1)
        #pragma unroll
        for (int e = 0; e < 4; ++e)
            s[e] += __shfl_xor(s[e], off);
    if (lane == 0)
        #pragma unroll
        for (int e = 0; e < 4; ++e)
            if (e0 + e < batch) out[e0 + e] = s[e];
}

extern "C" void kernel_launch(void* const* d_in, const int* in_sizes, int n_in,
                              void* d_out, int out_size, void* d_ws, size_t ws_size,
                              hipStream_t stream) {
    const float* f0  = (const float*)d_in[0];
    const float* f1  = (const float*)d_in[1];
    const float* f2  = (const float*)d_in[2];
    const float* f3  = (const float*)d_in[3];
    const int*   idx = (const int*)d_in[4];
    float* out = (float*)d_out;
    const int batch = out_size;

    const size_t ws_needed = (size_t)4 * FELEMS * sizeof(__half);  // 1 MiB
    if (ws_size >= ws_needed) {
        __half* wsf = (__half*)d_ws;
        dim3 cgrid(FELEMS / (256 * 8), 4);       // 64 x 4 blocks
        cp_convert_f16<<<cgrid, 256, 0, stream>>>(f0, f1, f2, f3, wsf);
        const int grid = (batch + 15) / 16;      // 4 waves/block, 4 elems/wave
        cp_gather_f16<<<grid, 256, 0, stream>>>(wsf, idx, out, batch);
    } else {
        const int grid = (batch + 15) / 16;
        cp_gather_f32<<<grid, 256, 0, stream>>>(f0, f1, f2, f3, idx, out, batch);
    }
}

// Round 6
// 24.453 us; speedup vs baseline: 1.0794x; 1.0794x over previous
//
#include <hip/hip_runtime.h>
#include <hip/hip_fp16.h>

// TensorCPFactorization: value[b] = sum_r prod_i f_i[idx[b,i], r]
// DIM=512, RANK=256, ORDER=4, BATCH=100000, f32 factors.
//
// R6: LDS-staged rank-sliced gather. Global-gather is per-wave-load bound
// (~32 clk/load regardless of bytes, R2/R5 evidence), so move the gather to
// LDS (128 B/clk/CU). 16 rank-slices of width 16; each block stages one
// slice of all 4 factors (64KB f16) and computes partial dots for a 3125-
// element chunk with lane-per-element LDS reads (XOR-swizzled b64 granules
// -> ~4-way conflicts = 1.58x). Pipeline: convert (f32->f16 slice-major ws)
// -> main (stage + gather -> partials[16][B]) -> reduce (sum 16 partials).

#define DIM    512
#define RANK   256
#define W      16                 // rank-slice width
#define NS     16                 // slices = RANK/W
#define NCHUNK 32                 // element chunks
#define FELEMS (DIM * RANK)       // 131072 per factor

// ---- pass 1: f32 -> f16, slice-major ws layout [s][f][i][16] --------------
__global__ __launch_bounds__(256) void cp_convert(
    const float* __restrict__ f0, const float* __restrict__ f1,
    const float* __restrict__ f2, const float* __restrict__ f3,
    __half* __restrict__ wsf)
{
    const float* srcs[4] = {f0, f1, f2, f3};
    const int f = blockIdx.y;
    const int g = blockIdx.x * 256 + threadIdx.x;   // granule of 4 f32
    if (g >= FELEMS / 4) return;
    const float4 v = *reinterpret_cast<const float4*>(srcs[f] + (size_t)g * 4);
    const int i = g >> 6;             // row
    const int s = (g >> 2) & 15;      // slice
    const int r = (g & 3) * 4;        // rank within slice
    union { uint2 u; __half2 h[2]; } pk;
    pk.h[0] = __float22half2_rn(make_float2(v.x, v.y));
    pk.h[1] = __float22half2_rn(make_float2(v.z, v.w));
    *reinterpret_cast<uint2*>(wsf + (((size_t)(s * 4 + f) * DIM + i) * W + r)) = pk.u;
}

// ---- pass 2: stage slice in LDS, gather partial dots ----------------------
// LDS: [4][512][4] uint2 granules (4 f16 each), granule index XOR-swizzled
// by (i>>2)&3 so random rows spread over all 16 even bank-slots.
__global__ __launch_bounds__(1024) void cp_main(
    const __half* __restrict__ wsf, const int* __restrict__ idx,
    float* __restrict__ partials, int batch)
{
    extern __shared__ char smem[];
    uint2* lds64 = reinterpret_cast<uint2*>(smem);   // 8192 granules = 64KB

    const int s     = blockIdx.x & (NS - 1);
    const int chunk = blockIdx.x >> 4;               // 0..31

    // stage: 4096 x 16B contiguous reads -> 8192 swizzled b64 writes
    const uint4* src16 = reinterpret_cast<const uint4*>(wsf + (size_t)s * (4 * DIM * W));
    for (int g = threadIdx.x; g < 4096; g += 1024) {
        const uint4 v  = src16[g];
        const int gg   = (g & 1) * 2;        // first b64-granule of this 16B
        const int i    = (g >> 1) & 511;
        const int f    = g >> 10;
        const int sw   = (i >> 2) & 3;
        const int base = f * 2048 + i * 4;
        lds64[base + (gg ^ sw)]       = make_uint2(v.x, v.y);
        lds64[base + ((gg + 1) ^ sw)] = make_uint2(v.z, v.w);
    }
    __syncthreads();

    // gather: lane-per-element
    const int csz = batch / NCHUNK;                  // 3125
    const int e0  = chunk * csz;
    float* pout = partials + (size_t)s * batch;
    for (int k = threadIdx.x; k < csz; k += 1024) {
        const int e = e0 + k;
        const int4 iv = *reinterpret_cast<const int4*>(idx + (size_t)e * 4);
        const int b0 = iv.x * 4,        sw0 = (iv.x >> 2) & 3;
        const int b1 = 2048 + iv.y * 4, sw1 = (iv.y >> 2) & 3;
        const int b2 = 4096 + iv.z * 4, sw2 = (iv.z >> 2) & 3;
        const int b3 = 6144 + iv.w * 4, sw3 = (iv.w >> 2) & 3;
        float acc = 0.f;
        #pragma unroll
        for (int g = 0; g < 4; ++g) {
            const uint2 h0 = lds64[b0 + (g ^ sw0)];
            const uint2 h1 = lds64[b1 + (g ^ sw1)];
            const uint2 h2 = lds64[b2 + (g ^ sw2)];
            const uint2 h3 = lds64[b3 + (g ^ sw3)];
            const __half2* a = reinterpret_cast<const __half2*>(&h0);
            const __half2* b = reinterpret_cast<const __half2*>(&h1);
            const __half2* c = reinterpret_cast<const __half2*>(&h2);
            const __half2* d = reinterpret_cast<const __half2*>(&h3);
            const float2 a0 = __half22float2(a[0]), a1 = __half22float2(a[1]);
            const float2 bb0 = __half22float2(b[0]), bb1 = __half22float2(b[1]);
            const float2 c0 = __half22float2(c[0]), c1 = __half22float2(c[1]);
            const float2 d0 = __half22float2(d[0]), d1 = __half22float2(d[1]);
            acc += a0.x * bb0.x * c0.x * d0.x;
            acc += a0.y * bb0.y * c0.y * d0.y;
            acc += a1.x * bb1.x * c1.x * d1.x;
            acc += a1.y * bb1.y * c1.y * d1.y;
        }
        pout[e] = acc;
    }
}

// ---- pass 3: out[e] = sum_s partials[s][e] --------------------------------
__global__ __launch_bounds__(256) void cp_reduce(
    const float* __restrict__ partials, float* __restrict__ out, int batch)
{
    const int e = (blockIdx.x * 256 + threadIdx.x) * 4;
    if (e >= batch) return;
    float4 acc = make_float4(0.f, 0.f, 0.f, 0.f);
    #pragma unroll
    for (int s = 0; s < NS; ++s) {
        const float4 v = *reinterpret_cast<const float4*>(partials + (size_t)s * batch + e);
        acc.x += v.x; acc.y += v.y; acc.z += v.z; acc.w += v.w;
    }
    *reinterpret_cast<float4*>(out + e) = acc;
}

// ---- fallback: R2 f32 direct gather (proven 21.4us) -----------------------
__global__ __launch_bounds__(256) void cp_gather_f32(
    const float* __restrict__ f0, const float* __restrict__ f1,
    const float* __restrict__ f2, const float* __restrict__ f3,
    const int*   __restrict__ idx,
    float*       __restrict__ out, int batch)
{
    const int wid  = (int)((blockIdx.x * blockDim.x + threadIdx.x) >> 6);
    const int lane = (int)(threadIdx.x & 63);
    const int e0   = wid * 4;
    if (e0 >= batch) return;
    const int r = lane * 4;
    float s[4];
    #pragma unroll
    for (int e = 0; e < 4; ++e) {
        const int  ec = (e0 + e) < batch ? (e0 + e) : batch - 1;
        const int4 iv = *reinterpret_cast<const int4*>(idx + (size_t)ec * 4);
        const float4 a = *reinterpret_cast<const float4*>(f0 + (size_t)iv.x * RANK + r);
        const float4 b = *reinterpret_cast<const float4*>(f1 + (size_t)iv.y * RANK + r);
        const float4 c = *reinterpret_cast<const float4*>(f2 + (size_t)iv.z * RANK + r);
        const float4 d = *reinterpret_cast<const float4*>(f3 + (size_t)iv.w * RANK + r);
        s[e] = a.x * b.x * c.x * d.x + a.y * b.y * c.y * d.y
             + a.z * b.z * c.z * d.z + a.w * b.w * c.w * d.w;
    }
    #pragma unroll
    for (int off = 32; off > 0; off >>= 1)
        #pragma unroll
        for (int e = 0; e < 4; ++e)
            s[e] += __shfl_xor(s[e], off);
    if (lane == 0)
        #pragma unroll
        for (int e = 0; e < 4; ++e)
            if (e0 + e < batch) out[e0 + e] = s[e];
}

extern "C" void kernel_launch(void* const* d_in, const int* in_sizes, int n_in,
                              void* d_out, int out_size, void* d_ws, size_t ws_size,
                              hipStream_t stream) {
    const float* f0  = (const float*)d_in[0];
    const float* f1  = (const float*)d_in[1];
    const float* f2  = (const float*)d_in[2];
    const float* f3  = (const float*)d_in[3];
    const int*   idx = (const int*)d_in[4];
    float* out = (float*)d_out;
    const int batch = out_size;

    const size_t f16_bytes = (size_t)4 * FELEMS * sizeof(__half);     // 1 MiB
    const size_t ws_needed = f16_bytes + (size_t)NS * batch * sizeof(float);

    if (ws_size >= ws_needed && batch % NCHUNK == 0 && batch % 4 == 0) {
        __half* wsf      = (__half*)d_ws;
        float*  partials = (float*)((char*)d_ws + f16_bytes);
        cp_convert<<<dim3(FELEMS / 4 / 256, 4), 256, 0, stream>>>(f0, f1, f2, f3, wsf);
        cp_main<<<NS * NCHUNK, 1024, 65536, stream>>>(wsf, idx, partials, batch);
        cp_reduce<<<(batch / 4 + 255) / 256, 256, 0, stream>>>(partials, out, batch);
    } else {
        const int grid = (batch + 15) / 16;
        cp_gather_f32<<<grid, 256, 0, stream>>>(f0, f1, f2, f3, idx, out, batch);
    }
}

// Round 7
// 23.503 us; speedup vs baseline: 1.1231x; 1.0404x over previous
//
#include <hip/hip_runtime.h>
#include <hip/hip_bf16.h>

// TensorCPFactorization: value[b] = sum_r prod_i f_i[idx[b,i], r]
// DIM=512, RANK=256, ORDER=4, BATCH=100000, f32 factors.
//
// R7: vmem gather is walled at ~33clk per wave-load regardless of width
// (R2/R4/R5 fits). Move the gather to LDS with a bank-safe layout:
//  - 16 rank-slices of W=16 f32; granule = 64B = 4 lanes x ds_read_b128,
//    each granule covers 16 banks exactly once -> random rows give only
//    row-parity Binomial imbalance (~1.2x), unlike R6's 8B scatter.
//  - pass1 reshuffles factors slice-major so staging is contiguous.
//  - index distribution + quad reduce via DPP quad_perm (VALU pipe),
//    keeping DS purely for gather data.
//  - partials as bf16 -> ws = 2MB + 3.2MB = 5.2MB (<= 7.4MB proven in R6).
//  - 128KB dynamic LDS via hipFuncSetAttribute; ANY failure -> proven R2
//    fallback kernel (21.4us), so correctness never depends on the attr.

#define DIM    512
#define RANK   256
#define W      16                  // rank-slice width (f32)
#define NS     16                  // slices = RANK/W
#define NCHUNK 16                  // element chunks (grid = NS*NCHUNK = 256)
#define FELEMS (DIM * RANK)

typedef float f32x4 __attribute__((ext_vector_type(4)));

// ---- pass 1: reshuffle f32 row-major -> slice-major [s][f][i][16] ---------
__global__ __launch_bounds__(256) void cp_reshuffle(
    const float* __restrict__ f0, const float* __restrict__ f1,
    const float* __restrict__ f2, const float* __restrict__ f3,
    float* __restrict__ wsA)
{
    const int g = blockIdx.x * 256 + threadIdx.x;   // granule id, NS*4*DIM total
    if (g >= NS * 4 * DIM) return;
    const int i = g & (DIM - 1);
    const int f = (g >> 9) & 3;
    const int s = g >> 11;
    const float* srcs[4] = {f0, f1, f2, f3};
    const f32x4* src = reinterpret_cast<const f32x4*>(srcs[f] + (size_t)i * RANK + s * W);
    f32x4* dst = reinterpret_cast<f32x4*>(wsA + (size_t)g * W);
    dst[0] = src[0]; dst[1] = src[1]; dst[2] = src[2]; dst[3] = src[3];
}

// ---- pass 2: stage slice (128KB) in LDS, gather partial dots --------------
__global__ __launch_bounds__(1024) void cp_main(
    const float* __restrict__ wsA, const int* __restrict__ idx,
    __hip_bfloat16* __restrict__ partials, int batch)
{
    extern __shared__ f32x4 lds4[];   // 8192 x float4 = 128KB: [(f*512+i)*4 + q]
    const int s     = blockIdx.x & (NS - 1);
    const int chunk = blockIdx.x >> 4;

    // stage: contiguous 128KB read -> linear b128 LDS writes (conflict-free)
    const f32x4* src = reinterpret_cast<const f32x4*>(wsA + (size_t)s * (4 * DIM * W));
    for (int t = threadIdx.x; t < (4 * DIM * W) / 4; t += 1024)
        lds4[t] = src[t];
    __syncthreads();

    const int csz  = batch / NCHUNK;       // 6250
    const int e0b  = chunk * csz;
    const int lane = (int)(threadIdx.x & 63);
    const int wid  = (int)(threadIdx.x >> 6);   // 16 waves
    const int q    = lane & 3;
    const int eoff = lane >> 2;                 // 16 elements per wave-iter
    const int iters = (csz + 255) / 256;        // block covers 256 elems/iter
    const int lim   = batch * 4 - 1;

    __hip_bfloat16* pout = partials + (size_t)s * batch;

    for (int it = 0; it < iters; ++it) {
        const int e0 = e0b + it * 256 + wid * 16;   // wave's first element
        const int e  = e0 + eoff;
        const bool valid = (e - e0b) < csz;

        // coalesced per-lane index load: lane l holds idx[e0 + l>>2][l&3]
        int ia = e0 * 4 + lane;
        ia = ia < lim ? ia : lim;
        const int myi = idx[ia];

        // broadcast each factor's index within the quad via DPP quad_perm
        const int i0 = __builtin_amdgcn_mov_dpp(myi, 0x00, 0xf, 0xf, true); // [0,0,0,0]
        const int i1 = __builtin_amdgcn_mov_dpp(myi, 0x55, 0xf, 0xf, true); // [1,1,1,1]
        const int i2 = __builtin_amdgcn_mov_dpp(myi, 0xaa, 0xf, 0xf, true); // [2,2,2,2]
        const int i3 = __builtin_amdgcn_mov_dpp(myi, 0xff, 0xf, 0xf, true); // [3,3,3,3]

        // 4 x ds_read_b128: granule (f,row) = 64B over 16 banks exactly once
        const f32x4 a = lds4[(0 * DIM + i0) * 4 + q];
        const f32x4 b = lds4[(1 * DIM + i1) * 4 + q];
        const f32x4 c = lds4[(2 * DIM + i2) * 4 + q];
        const f32x4 d = lds4[(3 * DIM + i3) * 4 + q];

        const f32x4 p = a * b * c * d;
        float sum = (p.x + p.y) + (p.z + p.w);

        // quad reduction via DPP xor1 [1,0,3,2]=0xB1, xor2 [2,3,0,1]=0x4E
        sum += __int_as_float(__builtin_amdgcn_mov_dpp(__float_as_int(sum), 0xB1, 0xf, 0xf, true));
        sum += __int_as_float(__builtin_amdgcn_mov_dpp(__float_as_int(sum), 0x4E, 0xf, 0xf, true));

        if (q == 0 && valid)
            pout[e] = __float2bfloat16(sum);
    }
}

// ---- pass 3: out[e] = sum_s partials[s][e] --------------------------------
__global__ __launch_bounds__(256) void cp_reduce(
    const __hip_bfloat16* __restrict__ partials, float* __restrict__ out, int batch)
{
    const int e = (blockIdx.x * 256 + threadIdx.x) * 4;
    if (e >= batch) return;
    float ax = 0.f, ay = 0.f, az = 0.f, aw = 0.f;
    #pragma unroll
    for (int s = 0; s < NS; ++s) {
        const uint2 u = *reinterpret_cast<const uint2*>(
            reinterpret_cast<const unsigned short*>(partials) + (size_t)s * batch + e);
        ax += __uint_as_float(u.x << 16);
        ay += __uint_as_float(u.x & 0xffff0000u);
        az += __uint_as_float(u.y << 16);
        aw += __uint_as_float(u.y & 0xffff0000u);
    }
    float4 acc = make_float4(ax, ay, az, aw);
    *reinterpret_cast<float4*>(out + e) = acc;
}

// ---- fallback: R2 f32 direct gather (proven 21.4us) -----------------------
__global__ __launch_bounds__(256) void cp_gather_f32(
    const float* __restrict__ f0, const float* __restrict__ f1,
    const float* __restrict__ f2, const float* __restrict__ f3,
    const int*   __restrict__ idx,
    float*       __restrict__ out, int batch)
{
    const int wid  = (int)((blockIdx.x * blockDim.x + threadIdx.x) >> 6);
    const int lane = (int)(threadIdx.x & 63);
    const int e0   = wid * 4;
    if (e0 >= batch) return;
    const int r = lane * 4;
    float s[4];
    #pragma unroll
    for (int e = 0; e < 4; ++e) {
        const int  ec = (e0 + e) < batch ? (e0 + e) : batch - 1;
        const int4 iv = *reinterpret_cast<const int4*>(idx + (size_t)ec * 4);
        const float4 a = *reinterpret_cast<const float4*>(f0 + (size_t)iv.x * RANK + r);
        const float4 b = *reinterpret_cast<const float4*>(f1 + (size_t)iv.y * RANK + r);
        const float4 c = *reinterpret_cast<const float4*>(f2 + (size_t)iv.z * RANK + r);
        const float4 d = *reinterpret_cast<const float4*>(f3 + (size_t)iv.w * RANK + r);
        s[e] = a.x * b.x * c.x * d.x + a.y * b.y * c.y * d.y
             + a.z * b.z * c.z * d.z + a.w * b.w * c.w * d.w;
    }
    #pragma unroll
    for (int off = 32; off > 0; off >>= 1)
        #pragma unroll
        for (int e = 0; e < 4; ++e)
            s[e] += __shfl_xor(s[e], off);
    if (lane == 0)
        #pragma unroll
        for (int e = 0; e < 4; ++e)
            if (e0 + e < batch) out[e0 + e] = s[e];
}

extern "C" void kernel_launch(void* const* d_in, const int* in_sizes, int n_in,
                              void* d_out, int out_size, void* d_ws, size_t ws_size,
                              hipStream_t stream) {
    const float* f0  = (const float*)d_in[0];
    const float* f1  = (const float*)d_in[1];
    const float* f2  = (const float*)d_in[2];
    const float* f3  = (const float*)d_in[3];
    const int*   idx = (const int*)d_in[4];
    float* out = (float*)d_out;
    const int batch = out_size;

    const size_t wsA_bytes  = (size_t)NS * 4 * DIM * W * sizeof(float);        // 2 MiB
    const size_t part_bytes = (size_t)NS * batch * sizeof(__hip_bfloat16);     // 3.2 MB
    const size_t ws_needed  = wsA_bytes + part_bytes;
    const int    lds_bytes  = 4 * DIM * W * (int)sizeof(float);                // 128 KiB

    bool main_path = (ws_size >= ws_needed) && (batch % NCHUNK == 0) && (batch % 4 == 0);
    if (main_path) {
        // opt into >64KB dynamic LDS; any failure -> safe fallback
        hipError_t err = hipFuncSetAttribute(
            reinterpret_cast<const void*>(&cp_main),
            hipFuncAttributeMaxDynamicSharedMemorySize, lds_bytes);
        if (err != hipSuccess) main_path = false;
    }

    if (main_path) {
        float*            wsA      = (float*)d_ws;
        __hip_bfloat16*   partials = (__hip_bfloat16*)((char*)d_ws + wsA_bytes);
        cp_reshuffle<<<(NS * 4 * DIM + 255) / 256, 256, 0, stream>>>(f0, f1, f2, f3, wsA);
        cp_main<<<NS * NCHUNK, 1024, lds_bytes, stream>>>(wsA, idx, partials, batch);
        cp_reduce<<<(batch / 4 + 255) / 256, 256, 0, stream>>>(partials, out, batch);
    } else {
        const int grid = (batch + 15) / 16;
        cp_gather_f32<<<grid, 256, 0, stream>>>(f0, f1, f2, f3, idx, out, batch);
    }
}